// Round 11
// baseline (5355.186 us; speedup 1.0000x reference)
//
#include <hip/hip_runtime.h>
#include <cmath>

#define HID 150
#define FOURH 600
#define BATCH 64
#define TLEN 2048
#define NKS 5  // 32-wide k-slices over k padded 150->160

typedef _Float16 f16;
typedef __attribute__((ext_vector_type(2))) _Float16 half2_t;
typedef __attribute__((ext_vector_type(8))) _Float16 f16x8;
typedef __attribute__((ext_vector_type(4))) float f32x4;

#if defined(__has_builtin)
#if __has_builtin(__builtin_amdgcn_fdot2)
#define FDOT2(a, b, c) __builtin_amdgcn_fdot2((a), (b), (c), false)
#endif
#endif
#ifndef FDOT2
__device__ __forceinline__ float fdot2_fb(half2_t a, half2_t b, float c) {
    return c + (float)a.x * (float)b.x + (float)a.y * (float)b.y;
}
#define FDOT2(a, b, c) fdot2_fb((a), (b), (c))
#endif

__device__ __forceinline__ float sigmoidf_(float x) {
    return 1.0f / (1.0f + __expf(-x));
}
__device__ __forceinline__ float tanhf_(float x) {
    return 1.0f - 2.0f / (__expf(2.0f * x) + 1.0f);
}

#define H2(x) __builtin_bit_cast(half2_t, (x))

// ======================= packing kernels =======================

// Wh -> slot-major coalesced half2 (r8 layout, verified):
// granule idx = (f*750 + t)*4 + e; f = Q*4+g; t = ks*150+j; covers
// k-pair k0 = ks*32 + Q*8 + 2e of gate g, unit j. A wave's float4 load of
// slot f is lane-contiguous (1 KB/instruction).
__global__ void pack_wh2(const float* __restrict__ Wh0, const float* __restrict__ Wh1,
                         half2_t* __restrict__ dst) {
    int idx = blockIdx.x * 256 + threadIdx.x;
    if (idx >= 96000) return;
    int layer = idx / 48000, r = idx - layer * 48000;
    int e = r & 3, f4 = r >> 2;
    int f = f4 / 750, t = f4 - f * 750;
    int ks = t / HID, j = t - ks * HID;
    int Q = f >> 2, g = f & 3;
    int k0 = ks * 32 + Q * 8 + 2 * e;
    const float* Wh = layer ? Wh1 : Wh0;
    float a  = (k0 < HID)     ? Wh[(size_t)k0 * FOURH + g * HID + j]       : 0.f;
    float bb = (k0 + 1 < HID) ? Wh[(size_t)(k0 + 1) * FOURH + g * HID + j] : 0.f;
    half2_t h; h.x = (_Float16)a; h.y = (_Float16)bb;
    dst[idx] = h;
}

// Wx -> MFMA B-frags (layout verified on-device in r9):
// wxp[layer][f=ct*5+k5][lane][e] = Wx[k][n], n=ct*16+(lane&15), k=k5*32+(lane>>4)*8+e
#define WXP_PER_LAYER (38 * 5 * 64 * 8)
__global__ void pack_wxm(const float* __restrict__ Wx0, const float* __restrict__ Wx1,
                         f16* __restrict__ dst) {
    int idx = blockIdx.x * 256 + threadIdx.x;
    if (idx >= 2 * WXP_PER_LAYER) return;
    int layer = idx / WXP_PER_LAYER, r = idx - layer * WXP_PER_LAYER;
    int e = r & 7;
    int lane = (r >> 3) & 63;
    int f = r >> 9;                  // ct*5 + k5
    int k5 = f % 5, ct = f / 5;
    int n = ct * 16 + (lane & 15);
    int k = k5 * 32 + (lane >> 4) * 8 + e;
    const float* Wx = layer ? Wx1 : Wx0;
    float v = (n < FOURH && k < HID) ? Wx[(size_t)k * FOURH + n] : 0.f;
    dst[idx] = (f16)v;
}

// ======================= xproj via MFMA (r10, working) =======================
__global__ __launch_bounds__(256) void xproj_mfma(
    int nA, const float* __restrict__ XA, const f16* __restrict__ wxA,
    const float* __restrict__ biasA, float* __restrict__ xdA, int tA,
    const float* __restrict__ XB, const f16* __restrict__ wxB,
    const float* __restrict__ biasB, float* __restrict__ xdB, int tB,
    int C)
{
    const int xg = C / 32;
    const int per = 64 * xg;
    int x = blockIdx.x;
    const int isB = (x >= nA * per) ? 1 : 0;
    if (isB) x -= nA * per;
    const float* X    = isB ? XB    : XA;
    const f16*   wx   = isB ? wxB   : wxA;
    const float* bias = isB ? biasB : biasA;
    float*       xd   = isB ? xdB   : xdA;
    const int    t0   = isB ? tB    : tA;

    const int b  = x / xg;
    const int i0 = (x - b * xg) * 32;
    const int tid = threadIdx.x;
    const int wv = tid >> 6;
    const int l  = tid & 63;

    __shared__ __align__(16) f16 Xs[32][168];

    const float* Xbase = X + ((size_t)(b * TLEN + t0 + i0)) * HID;
    #pragma unroll
    for (int it = 0; it < 20; ++it) {
        int idx = tid + it * 256;
        int r = idx / 160, k = idx - r * 160;
        Xs[r][k] = (f16)((k < HID) ? Xbase[(size_t)r * HID + k] : 0.f);
    }
    __syncthreads();

    f16x8 af[2][NKS];
    #pragma unroll
    for (int mt = 0; mt < 2; ++mt)
        #pragma unroll
        for (int k5 = 0; k5 < NKS; ++k5)
            af[mt][k5] = *(const f16x8*)&Xs[mt * 16 + (l & 15)][k5 * 32 + (l >> 4) * 8];

    const int n_lo = l & 15;
    const int r0 = (l >> 4) * 4;
    for (int ct = wv; ct < 38; ct += 4) {
        const f16* wb = wx + ((size_t)(ct * 5) * 64 + l) * 8;
        f32x4 acc0 = {0.f, 0.f, 0.f, 0.f};
        f32x4 acc1 = {0.f, 0.f, 0.f, 0.f};
        #pragma unroll
        for (int k5 = 0; k5 < NKS; ++k5) {
            f16x8 bf = *(const f16x8*)(wb + (size_t)k5 * 64 * 8);
            acc0 = __builtin_amdgcn_mfma_f32_16x16x32_f16(af[0][k5], bf, acc0, 0, 0, 0);
            acc1 = __builtin_amdgcn_mfma_f32_16x16x32_f16(af[1][k5], bf, acc1, 0, 0, 0);
        }
        const int n = ct * 16 + n_lo;
        if (n < FOURH) {
            float bv = bias[n];
            float* o = xd + ((size_t)b * C + i0) * FOURH + n;
            #pragma unroll
            for (int r = 0; r < 4; ++r) {
                o[(size_t)(r0 + r) * FOURH]      = acc0[r] + bv;
                o[(size_t)(16 + r0 + r) * FOURH] = acc1[r] + bv;
            }
        }
    }
}

// ======================= recurrence: G=2, gate-pair passes =======================
// 4 fdot2 of one (h float4, w float4) pair
#define D4(acc, hf, wf) \
  acc = FDOT2(H2((hf).x), H2((wf).x), acc); \
  acc = FDOT2(H2((hf).y), H2((wf).y), acc); \
  acc = FDOT2(H2((hf).z), H2((wf).z), acc); \
  acc = FDOT2(H2((hf).w), H2((wf).w), acc);

// One gate-pair pass (gates gb, gb+1) over both batches. Live set kept small:
// 8 weight float4 + 4 acc + h reads (transient). Weight loads lane-contiguous.
#define PASS(gb) { \
  float4 wa0 = Ws[(0 * 4 + (gb)) * 750 + tidc]; \
  float4 wa1 = Ws[(1 * 4 + (gb)) * 750 + tidc]; \
  float4 wa2 = Ws[(2 * 4 + (gb)) * 750 + tidc]; \
  float4 wa3 = Ws[(3 * 4 + (gb)) * 750 + tidc]; \
  float4 wb0 = Ws[(0 * 4 + (gb) + 1) * 750 + tidc]; \
  float4 wb1 = Ws[(1 * 4 + (gb) + 1) * 750 + tidc]; \
  float4 wb2 = Ws[(2 * 4 + (gb) + 1) * 750 + tidc]; \
  float4 wb3 = Ws[(3 * 4 + (gb) + 1) * 750 + tidc]; \
  float au = 0.f, av = 0.f, bu = 0.f, bv = 0.f; \
  { float4 hu = *(const float4*)(const void*)&h16[0][ks * 32 + 0];  \
    float4 hv = *(const float4*)(const void*)&h16[1][ks * 32 + 0];  \
    D4(au, hu, wa0) D4(av, hv, wa0) D4(bu, hu, wb0) D4(bv, hv, wb0) } \
  { float4 hu = *(const float4*)(const void*)&h16[0][ks * 32 + 8];  \
    float4 hv = *(const float4*)(const void*)&h16[1][ks * 32 + 8];  \
    D4(au, hu, wa1) D4(av, hv, wa1) D4(bu, hu, wb1) D4(bv, hv, wb1) } \
  { float4 hu = *(const float4*)(const void*)&h16[0][ks * 32 + 16]; \
    float4 hv = *(const float4*)(const void*)&h16[1][ks * 32 + 16]; \
    D4(au, hu, wa2) D4(av, hv, wa2) D4(bu, hu, wb2) D4(bv, hv, wb2) } \
  { float4 hu = *(const float4*)(const void*)&h16[0][ks * 32 + 24]; \
    float4 hv = *(const float4*)(const void*)&h16[1][ks * 32 + 24]; \
    D4(au, hu, wa3) D4(av, hv, wa3) D4(bu, hu, wb3) D4(bv, hv, wb3) } \
  part_s[0][ks][(gb)][j]     = au; \
  part_s[1][ks][(gb)][j]     = av; \
  part_s[0][ks][(gb) + 1][j] = bu; \
  part_s[1][ks][(gb) + 1][j] = bv; }

// G=2: WG handles batches {2bg, 2bg+1}; each weight byte fetched from L2 is
// used for BOTH batches -> chip-wide L2 weight demand halves vs G=1.
// Dual grid 64: WGs 0-31 part A, 32-63 part B. Single grid 32: part A.
__global__ __launch_bounds__(768)
__attribute__((amdgpu_waves_per_eu(3, 3)))
void lstm_recur4(const float* __restrict__ xpA, const float4* __restrict__ whsA,
                 float* __restrict__ stA, int t0A,
                 const float* __restrict__ xpB, const float4* __restrict__ whsB,
                 float* __restrict__ stB, int t0B,
                 float* __restrict__ out, int C)
{
    const int part = blockIdx.x >> 5;
    const int b0 = (blockIdx.x & 31) * 2;
    const int tid = threadIdx.x;
    const int tidc = (tid < 750) ? tid : 749;
    const int ks = tidc / HID;       // 0..4
    const int j  = tidc - ks * HID;  // 0..149

    const float*  xp    = part ? xpB  : xpA;
    const float4* Ws    = part ? whsB : whsA;
    float*        state = part ? stB  : stA;
    const int     t0    = part ? t0B  : t0A;

    __shared__ __align__(16) _Float16 h16[2][160];          // h as f16, tails zero
    __shared__ __align__(16) float part_s[2][NKS][4][152];  // [bb][ks][g][j]

    // Stage-B mapping: tid < 300 -> (bb, jj)
    const int tidb = (tid < 300) ? tid : 299;
    const int bb = tidb / HID;
    const int jj = tidb - bb * HID;

    if (tid < 320) {
        int hb = tid / 160, hj = tid - hb * 160;
        float hv = 0.f;
        if (t0 != 0 && hj < HID) hv = state[(b0 + hb) * 300 + HID + hj];
        h16[hb][hj] = (_Float16)hv;
    }
    float cst = 0.f;
    if (t0 != 0 && tid < 300) cst = state[(b0 + bb) * 300 + jj];
    __syncthreads();

    const float* xpb = xp + (size_t)(b0 + bb) * C * FOURH;
    float* outb = out + ((size_t)(b0 + bb) * TLEN + t0) * HID;

    float xn0 = 0.f, xn1 = 0.f, xn2 = 0.f, xn3 = 0.f;
    if (tid < 300) {
        xn0 = xpb[jj];
        xn1 = xpb[HID + jj];
        xn2 = xpb[2 * HID + jj];
        xn3 = xpb[3 * HID + jj];
    }

    for (int i = 0; i < C; ++i) {
        // ---- Stage A: two gate-pair passes, 128 fdot2/thread (750 thr) ----
        if (tid < 750) {
            PASS(0)
            PASS(2)
        }
        __syncthreads();

        // ---- Stage B: reduce, activate, update c/h (300 threads) ----
        if (tid < 300) {
            float p0 = xn0, p1 = xn1, p2 = xn2, p3 = xn3;
            if (i + 1 < C) {
                const float* p = &xpb[(size_t)(i + 1) * FOURH];
                xn0 = p[jj];
                xn1 = p[HID + jj];
                xn2 = p[2 * HID + jj];
                xn3 = p[3 * HID + jj];
            }
            float z0 = p0, z1 = p1, z2 = p2, z3 = p3;
            #pragma unroll
            for (int s = 0; s < NKS; ++s) {
                z0 += part_s[bb][s][0][jj];
                z1 += part_s[bb][s][1][jj];
                z2 += part_s[bb][s][2][jj];
                z3 += part_s[bb][s][3][jj];
            }
            float ig = sigmoidf_(z0);
            float fg = sigmoidf_(z1);
            float gg = tanhf_(z2);
            float og = sigmoidf_(z3);
            cst = fg * cst + ig * gg;
            float hn = og * tanhf_(cst);
            h16[bb][jj] = (_Float16)hn;
            outb[(size_t)i * HID + jj] = hn;
        }
        __syncthreads();
    }

    if (tid < 300) {
        state[(b0 + bb) * 300 + jj] = cst;
        state[(b0 + bb) * 300 + HID + jj] = (float)h16[bb][jj];
    }
}

extern "C" void kernel_launch(void* const* d_in, const int* in_sizes, int n_in,
                              void* d_out, int out_size, void* d_ws, size_t ws_size,
                              hipStream_t stream) {
    const float* xs  = (const float*)d_in[0];
    const float* Wx0 = (const float*)d_in[1];
    const float* Wh0 = (const float*)d_in[2];
    const float* b0  = (const float*)d_in[3];
    const float* Wx1 = (const float*)d_in[4];
    const float* Wh1 = (const float*)d_in[5];
    const float* b1  = (const float*)d_in[6];
    float* out = (float*)d_out;

    int C = 256;
    {
        size_t need = 2ull * BATCH * C * FOURH * 4 + 96000ull * 4
                    + 2ull * WXP_PER_LAYER * 2 + 2ull * BATCH * 300 * 4;
        if (need > ws_size) C = 128;
    }
    const size_t xpsz = (size_t)BATCH * C * FOURH * 4;
    char* p = (char*)d_ws;
    float* xp0 = (float*)p;      p += xpsz;
    float* xp1 = (float*)p;      p += xpsz;
    half2_t* whp = (half2_t*)p;  p += 96000ull * 4;
    f16* wxp = (f16*)p;          p += 2ull * WXP_PER_LAYER * 2;
    float* st0 = (float*)p;      p += (size_t)BATCH * 300 * 4;
    float* st1 = (float*)p;
    const float4* whs0 = (const float4*)whp;
    const float4* whs1 = (const float4*)(whp + 48000);
    const f16* wxp0 = wxp;
    const f16* wxp1 = wxp + WXP_PER_LAYER;

    pack_wh2<<<dim3((96000 + 255) / 256), dim3(256), 0, stream>>>(Wh0, Wh1, whp);
    pack_wxm<<<dim3((2 * WXP_PER_LAYER + 255) / 256), dim3(256), 0, stream>>>(Wx0, Wx1, wxp);

    const int nchunk = TLEN / C;
    const int xg = C / 32;

    // Slot s: xproj(L0 chunk s + L1 chunk s-1) then recur(L0 s || L1 s-1).
    for (int s = 0; s <= nchunk; ++s) {
        const int hasA = (s < nchunk) ? 1 : 0;
        const int hasB = (s >= 1) ? 1 : 0;
        xproj_mfma<<<dim3((hasA + hasB) * 64 * xg), dim3(256), 0, stream>>>(
            hasA, xs, wxp0, b0, xp0, s * C,
            out, wxp1, b1, xp1, (s - 1) * C, C);
        if (hasA && hasB)
            lstm_recur4<<<dim3(64), dim3(768), 0, stream>>>(
                xp0, whs0, st0, s * C, xp1, whs1, st1, (s - 1) * C, out, C);
        else if (hasA)
            lstm_recur4<<<dim3(32), dim3(768), 0, stream>>>(
                xp0, whs0, st0, s * C, xp0, whs0, st0, 0, out, C);
        else
            lstm_recur4<<<dim3(32), dim3(768), 0, stream>>>(
                xp1, whs1, st1, (s - 1) * C, xp1, whs1, st1, 0, out, C);
    }
}

// Round 12
// 3213.361 us; speedup vs baseline: 1.6665x; 1.6665x over previous
//
#include <hip/hip_runtime.h>
#include <cmath>

#define HID 150
#define FOURH 600
#define BATCH 64
#define TLEN 2048
#define NKS 5  // 32-wide k-slices over k padded 150->160

typedef _Float16 f16;
typedef __attribute__((ext_vector_type(2))) _Float16 half2_t;
typedef __attribute__((ext_vector_type(8))) _Float16 f16x8;
typedef __attribute__((ext_vector_type(4))) float f32x4;

#if defined(__has_builtin)
#if __has_builtin(__builtin_amdgcn_fdot2)
#define FDOT2(a, b, c) __builtin_amdgcn_fdot2((a), (b), (c), false)
#endif
#endif
#ifndef FDOT2
__device__ __forceinline__ float fdot2_fb(half2_t a, half2_t b, float c) {
    return c + (float)a.x * (float)b.x + (float)a.y * (float)b.y;
}
#define FDOT2(a, b, c) fdot2_fb((a), (b), (c))
#endif

__device__ __forceinline__ float sigmoidf_(float x) {
    return 1.0f / (1.0f + __expf(-x));
}
__device__ __forceinline__ float tanhf_(float x) {
    return 1.0f - 2.0f / (__expf(2.0f * x) + 1.0f);
}

#define H2(x) __builtin_bit_cast(half2_t, (x))

// ======================= packing kernels =======================

// Wh -> slot-major coalesced half2 (r8 layout, verified):
// granule idx = (f*750 + t)*4 + e; f = Q*4+g; t = ks*150+j; covers
// k-pair k0 = ks*32 + Q*8 + 2e of gate g, unit j. A wave's float4 load of
// slot f is lane-contiguous (1 KB/instruction). Slots 0..7 (Q=0,1) form a
// contiguous 96 KB block -> trivially LDS-stageable.
__global__ void pack_wh2(const float* __restrict__ Wh0, const float* __restrict__ Wh1,
                         half2_t* __restrict__ dst) {
    int idx = blockIdx.x * 256 + threadIdx.x;
    if (idx >= 96000) return;
    int layer = idx / 48000, r = idx - layer * 48000;
    int e = r & 3, f4 = r >> 2;
    int f = f4 / 750, t = f4 - f * 750;
    int ks = t / HID, j = t - ks * HID;
    int Q = f >> 2, g = f & 3;
    int k0 = ks * 32 + Q * 8 + 2 * e;
    const float* Wh = layer ? Wh1 : Wh0;
    float a  = (k0 < HID)     ? Wh[(size_t)k0 * FOURH + g * HID + j]       : 0.f;
    float bb = (k0 + 1 < HID) ? Wh[(size_t)(k0 + 1) * FOURH + g * HID + j] : 0.f;
    half2_t h; h.x = (_Float16)a; h.y = (_Float16)bb;
    dst[idx] = h;
}

// Wx -> MFMA B-frags (layout verified on-device in r9):
// wxp[layer][f=ct*5+k5][lane][e] = Wx[k][n], n=ct*16+(lane&15), k=k5*32+(lane>>4)*8+e
#define WXP_PER_LAYER (38 * 5 * 64 * 8)
__global__ void pack_wxm(const float* __restrict__ Wx0, const float* __restrict__ Wx1,
                         f16* __restrict__ dst) {
    int idx = blockIdx.x * 256 + threadIdx.x;
    if (idx >= 2 * WXP_PER_LAYER) return;
    int layer = idx / WXP_PER_LAYER, r = idx - layer * WXP_PER_LAYER;
    int e = r & 7;
    int lane = (r >> 3) & 63;
    int f = r >> 9;                  // ct*5 + k5
    int k5 = f % 5, ct = f / 5;
    int n = ct * 16 + (lane & 15);
    int k = k5 * 32 + (lane >> 4) * 8 + e;
    const float* Wx = layer ? Wx1 : Wx0;
    float v = (n < FOURH && k < HID) ? Wx[(size_t)k * FOURH + n] : 0.f;
    dst[idx] = (f16)v;
}

// ======================= xproj via MFMA (r10, working) =======================
__global__ __launch_bounds__(256) void xproj_mfma(
    int nA, const float* __restrict__ XA, const f16* __restrict__ wxA,
    const float* __restrict__ biasA, float* __restrict__ xdA, int tA,
    const float* __restrict__ XB, const f16* __restrict__ wxB,
    const float* __restrict__ biasB, float* __restrict__ xdB, int tB,
    int C)
{
    const int xg = C / 32;
    const int per = 64 * xg;
    int x = blockIdx.x;
    const int isB = (x >= nA * per) ? 1 : 0;
    if (isB) x -= nA * per;
    const float* X    = isB ? XB    : XA;
    const f16*   wx   = isB ? wxB   : wxA;
    const float* bias = isB ? biasB : biasA;
    float*       xd   = isB ? xdB   : xdA;
    const int    t0   = isB ? tB    : tA;

    const int b  = x / xg;
    const int i0 = (x - b * xg) * 32;
    const int tid = threadIdx.x;
    const int wv = tid >> 6;
    const int l  = tid & 63;

    __shared__ __align__(16) f16 Xs[32][168];

    const float* Xbase = X + ((size_t)(b * TLEN + t0 + i0)) * HID;
    #pragma unroll
    for (int it = 0; it < 20; ++it) {
        int idx = tid + it * 256;
        int r = idx / 160, k = idx - r * 160;
        Xs[r][k] = (f16)((k < HID) ? Xbase[(size_t)r * HID + k] : 0.f);
    }
    __syncthreads();

    f16x8 af[2][NKS];
    #pragma unroll
    for (int mt = 0; mt < 2; ++mt)
        #pragma unroll
        for (int k5 = 0; k5 < NKS; ++k5)
            af[mt][k5] = *(const f16x8*)&Xs[mt * 16 + (l & 15)][k5 * 32 + (l >> 4) * 8];

    const int n_lo = l & 15;
    const int r0 = (l >> 4) * 4;
    for (int ct = wv; ct < 38; ct += 4) {
        const f16* wb = wx + ((size_t)(ct * 5) * 64 + l) * 8;
        f32x4 acc0 = {0.f, 0.f, 0.f, 0.f};
        f32x4 acc1 = {0.f, 0.f, 0.f, 0.f};
        #pragma unroll
        for (int k5 = 0; k5 < NKS; ++k5) {
            f16x8 bf = *(const f16x8*)(wb + (size_t)k5 * 64 * 8);
            acc0 = __builtin_amdgcn_mfma_f32_16x16x32_f16(af[0][k5], bf, acc0, 0, 0, 0);
            acc1 = __builtin_amdgcn_mfma_f32_16x16x32_f16(af[1][k5], bf, acc1, 0, 0, 0);
        }
        const int n = ct * 16 + n_lo;
        if (n < FOURH) {
            float bv = bias[n];
            float* o = xd + ((size_t)b * C + i0) * FOURH + n;
            #pragma unroll
            for (int r = 0; r < 4; ++r) {
                o[(size_t)(r0 + r) * FOURH]      = acc0[r] + bv;
                o[(size_t)(16 + r0 + r) * FOURH] = acc1[r] + bv;
            }
        }
    }
}

// ======================= recurrence: G=1, LDS/L2 split weight stream =======================
// 4 fdot2 of one (h float4, w float4) pair
#define D4(acc, hf, wf) \
  acc = FDOT2(H2((hf).x), H2((wf).x), acc); \
  acc = FDOT2(H2((hf).y), H2((wf).y), acc); \
  acc = FDOT2(H2((hf).z), H2((wf).z), acc); \
  acc = FDOT2(H2((hf).w), H2((wf).w), acc);

// One quarter: h float4 x 4 gate weights
#define DQ(hq, wg0, wg1, wg2, wg3) \
  D4(a0, hq, wg0) D4(a1, hq, wg1) D4(a2, hq, wg2) D4(a3, hq, wg3)

// G=1, 768 thr, 128 WGs dual (r5 structure — best known). The 192 KB/step
// weight stream is the per-CU fetch bound (87 B/cy measured, r5/r7/r10
// journal). Split it across the two independent per-CU pipes: slots 0..7
// (96 KB, k-pairs Q=0,1) live in LDS (staged once, read via lgkmcnt pipe);
// slots 8..15 stream from L2 (vmcnt pipe). They overlap -> step floor drops
// from 2200 cy to ~1100 cy.
__global__ __launch_bounds__(768)
__attribute__((amdgpu_waves_per_eu(3, 3)))
void lstm_recur5(const float* __restrict__ xpA, const float4* __restrict__ whsA,
                 float* __restrict__ stA, int t0A,
                 const float* __restrict__ xpB, const float4* __restrict__ whsB,
                 float* __restrict__ stB, int t0B,
                 float* __restrict__ out, int C)
{
    const int part = blockIdx.x >> 6;
    const int b = blockIdx.x & 63;
    const int tid = threadIdx.x;
    const int tidc = (tid < 750) ? tid : 749;
    const int ks = tidc / HID;       // 0..4
    const int j  = tidc - ks * HID;  // 0..149

    const float*  xp    = part ? xpB  : xpA;
    const float4* Ws    = part ? whsB : whsA;
    float*        state = part ? stB  : stA;
    const int     t0    = part ? t0B  : t0A;

    __shared__ __align__(16) float4 ldsw[6000];             // 96 KB: slots 0..7
    __shared__ __align__(16) _Float16 h16[160];
    __shared__ __align__(16) float part_s[NKS][4][152];

    // ---- one-time: stage slots 0..7 (contiguous 96 KB) into LDS ----
    for (int x = tid; x < 6000; x += 768) ldsw[x] = Ws[x];

    float cst = 0.f;
    if (tid < 160) {
        float hv = 0.f;
        if (t0 != 0 && tid < HID) {
            cst = state[b * 300 + tid];
            hv  = state[b * 300 + HID + tid];
        }
        h16[tid] = (_Float16)hv;
    }
    __syncthreads();

    const float* xpb = xp + (size_t)b * C * FOURH;
    float* outb = out + ((size_t)b * TLEN + t0) * HID;

    float xn0 = 0.f, xn1 = 0.f, xn2 = 0.f, xn3 = 0.f;
    if (tid < HID) {
        xn0 = xpb[tid];
        xn1 = xpb[HID + tid];
        xn2 = xpb[2 * HID + tid];
        xn3 = xpb[3 * HID + tid];
    }

    for (int i = 0; i < C; ++i) {
        // ---- Stage A: 8 L2 + 8 LDS weight float4s, 64 fdot2 (750 thr) ----
        if (tid < 750) {
            // L2 stream first (long latency, vmcnt pipe)
            float4 g0 = Ws[ 8 * 750 + tidc];   // Q2,g0
            float4 g1 = Ws[ 9 * 750 + tidc];   // Q2,g1
            float4 g2 = Ws[10 * 750 + tidc];   // Q2,g2
            float4 g3 = Ws[11 * 750 + tidc];   // Q2,g3
            float4 g4 = Ws[12 * 750 + tidc];   // Q3,g0
            float4 g5 = Ws[13 * 750 + tidc];   // Q3,g1
            float4 g6 = Ws[14 * 750 + tidc];   // Q3,g2
            float4 g7 = Ws[15 * 750 + tidc];   // Q3,g3
            // LDS-resident half (lgkmcnt pipe)
            float4 l0 = ldsw[0 * 750 + tidc];  // Q0,g0
            float4 l1 = ldsw[1 * 750 + tidc];  // Q0,g1
            float4 l2 = ldsw[2 * 750 + tidc];  // Q0,g2
            float4 l3 = ldsw[3 * 750 + tidc];  // Q0,g3
            float4 l4 = ldsw[4 * 750 + tidc];  // Q1,g0
            float4 l5 = ldsw[5 * 750 + tidc];  // Q1,g1
            float4 l6 = ldsw[6 * 750 + tidc];  // Q1,g2
            float4 l7 = ldsw[7 * 750 + tidc];  // Q1,g3
            float4 h0 = *(const float4*)(const void*)&h16[ks * 32 + 0];
            float4 h1 = *(const float4*)(const void*)&h16[ks * 32 + 8];
            float4 h2 = *(const float4*)(const void*)&h16[ks * 32 + 16];
            float4 h3 = *(const float4*)(const void*)&h16[ks * 32 + 24];
            float a0 = 0.f, a1 = 0.f, a2 = 0.f, a3 = 0.f;
            DQ(h0, l0, l1, l2, l3)
            DQ(h2, g0, g1, g2, g3)
            DQ(h1, l4, l5, l6, l7)
            DQ(h3, g4, g5, g6, g7)
            part_s[ks][0][j] = a0;
            part_s[ks][1][j] = a1;
            part_s[ks][2][j] = a2;
            part_s[ks][3][j] = a3;
        }
        __syncthreads();

        // ---- Stage B: reduce, activate, update c/h (150 thr) ----
        if (tid < HID) {
            float p0 = xn0, p1 = xn1, p2 = xn2, p3 = xn3;
            if (i + 1 < C) {
                const float* p = &xpb[(size_t)(i + 1) * FOURH];
                xn0 = p[tid];
                xn1 = p[HID + tid];
                xn2 = p[2 * HID + tid];
                xn3 = p[3 * HID + tid];
            }
            float z0 = p0, z1 = p1, z2 = p2, z3 = p3;
            #pragma unroll
            for (int s = 0; s < NKS; ++s) {
                z0 += part_s[s][0][tid];
                z1 += part_s[s][1][tid];
                z2 += part_s[s][2][tid];
                z3 += part_s[s][3][tid];
            }
            float ig = sigmoidf_(z0);
            float fg = sigmoidf_(z1);
            float gg = tanhf_(z2);
            float og = sigmoidf_(z3);
            cst = fg * cst + ig * gg;
            float hn = og * tanhf_(cst);
            h16[tid] = (_Float16)hn;
            outb[(size_t)i * HID + tid] = hn;
        }
        __syncthreads();
    }

    if (tid < HID) {
        state[b * 300 + tid] = cst;
        state[b * 300 + HID + tid] = (float)h16[tid];
    }
}

extern "C" void kernel_launch(void* const* d_in, const int* in_sizes, int n_in,
                              void* d_out, int out_size, void* d_ws, size_t ws_size,
                              hipStream_t stream) {
    const float* xs  = (const float*)d_in[0];
    const float* Wx0 = (const float*)d_in[1];
    const float* Wh0 = (const float*)d_in[2];
    const float* b0  = (const float*)d_in[3];
    const float* Wx1 = (const float*)d_in[4];
    const float* Wh1 = (const float*)d_in[5];
    const float* b1  = (const float*)d_in[6];
    float* out = (float*)d_out;

    int C = 256;
    {
        size_t need = 2ull * BATCH * C * FOURH * 4 + 96000ull * 4
                    + 2ull * WXP_PER_LAYER * 2 + 2ull * BATCH * 300 * 4;
        if (need > ws_size) C = 128;
    }
    const size_t xpsz = (size_t)BATCH * C * FOURH * 4;
    char* p = (char*)d_ws;
    float* xp0 = (float*)p;      p += xpsz;
    float* xp1 = (float*)p;      p += xpsz;
    half2_t* whp = (half2_t*)p;  p += 96000ull * 4;
    f16* wxp = (f16*)p;          p += 2ull * WXP_PER_LAYER * 2;
    float* st0 = (float*)p;      p += (size_t)BATCH * 300 * 4;
    float* st1 = (float*)p;
    const float4* whs0 = (const float4*)whp;
    const float4* whs1 = (const float4*)(whp + 48000);
    const f16* wxp0 = wxp;
    const f16* wxp1 = wxp + WXP_PER_LAYER;

    pack_wh2<<<dim3((96000 + 255) / 256), dim3(256), 0, stream>>>(Wh0, Wh1, whp);
    pack_wxm<<<dim3((2 * WXP_PER_LAYER + 255) / 256), dim3(256), 0, stream>>>(Wx0, Wx1, wxp);

    const int nchunk = TLEN / C;
    const int xg = C / 32;

    // Slot s: xproj(L0 chunk s + L1 chunk s-1) then recur(L0 s || L1 s-1).
    for (int s = 0; s <= nchunk; ++s) {
        const int hasA = (s < nchunk) ? 1 : 0;
        const int hasB = (s >= 1) ? 1 : 0;
        xproj_mfma<<<dim3((hasA + hasB) * 64 * xg), dim3(256), 0, stream>>>(
            hasA, xs, wxp0, b0, xp0, s * C,
            out, wxp1, b1, xp1, (s - 1) * C, C);
        if (hasA && hasB)
            lstm_recur5<<<dim3(128), dim3(768), 0, stream>>>(
                xp0, whs0, st0, s * C, xp1, whs1, st1, (s - 1) * C, out, C);
        else if (hasA)
            lstm_recur5<<<dim3(64), dim3(768), 0, stream>>>(
                xp0, whs0, st0, s * C, xp0, whs0, st0, 0, out, C);
        else
            lstm_recur5<<<dim3(64), dim3(768), 0, stream>>>(
                xp1, whs1, st1, (s - 1) * C, xp1, whs1, st1, 0, out, C);
    }
}